// Round 8
// baseline (558.138 us; speedup 1.0000x reference)
//
#include <hip/hip_runtime.h>
#include <math.h>

#define N_NODES 10000
#define N_EDGES 320000
#define HIDDEN  128
#define NUM_RBF 20
#define H3      384   // 3*HIDDEN
#define FP_STRIDE 516 // f_pack row stride in ushorts (1032B)
#define RBF_STRIDE 40 // rbf_s row stride in ushorts (80B)
#define NPB 4         // target nodes per edge-block

typedef __attribute__((ext_vector_type(8))) short short8;
typedef __attribute__((ext_vector_type(8))) unsigned short ushort8v;
typedef __attribute__((ext_vector_type(4))) float floatx4;

__device__ __forceinline__ float b2f(ushort u) {
    unsigned v = ((unsigned)u) << 16; float f; __builtin_memcpy(&f, &v, 4); return f;
}
__device__ __forceinline__ ushort f2b(float f) {   // RNE f32 -> bf16
    unsigned x; __builtin_memcpy(&x, &f, 4);
    return (ushort)((x + 0x7fffu + ((x >> 16) & 1u)) >> 16);
}

// ---------------------------------------------------------------------------
// Kernel A (fused prep), grid-split:
//   seg0: src_pack mu slots (bf16)            (5000 blocks)
//   seg1: w_prep Wf2/W1/W2 + Wf1b(bias-fold)  (976 blocks)
//   seg2: histogram of targets                (1250 blocks; counts pre-memset)
// ---------------------------------------------------------------------------
#define A_PK 5000
#define A_W  976
#define A_H  1250

__device__ __forceinline__ void w_prep_one(const float* __restrict__ W,
                                           ushort* __restrict__ Wb, int idx) {
    const int k = idx / H3, j = idx % H3;
    const int kt = k >> 5, r = k & 31;
    const int hi = r >> 3, b = r & 7;
    const int nt = j >> 4, jj = j & 15;
    const int lane = hi * 16 + jj;
    Wb[(((kt * 24 + nt) * 64) + lane) * 8 + b] = f2b(W[k * H3 + j]);
}

__global__ __launch_bounds__(256) void prep_kernel(
    const float* __restrict__ mu,
    const float* __restrict__ Wf2, const float* __restrict__ W1,
    const float* __restrict__ W2,
    const float* __restrict__ Wf1, const float* __restrict__ bf1,
    const int* __restrict__ ei,
    ushort4* __restrict__ src_pack,
    ushort* __restrict__ Wf2b, ushort* __restrict__ W1b,
    ushort* __restrict__ W2b, ushort* __restrict__ Wf1b,
    int* __restrict__ counts) {

    const int b = blockIdx.x, t = threadIdx.x;
    if (b < A_PK) {
        const int i = b * 256 + t;                  // over N*128
        if (i < N_NODES * HIDDEN) {
            const int n = i >> 7, c = i & 127;
            ushort4 v;
            v.x = f2b(mu[(n * 3 + 0) * HIDDEN + c]);
            v.y = f2b(mu[(n * 3 + 1) * HIDDEN + c]);
            v.z = f2b(mu[(n * 3 + 2) * HIDDEN + c]);
            v.w = 0;
            src_pack[(size_t)i * 2 + 1] = v;        // slot 1 of 16B record
        }
    } else if (b < A_PK + A_W) {
        const int i = (b - A_PK) * 256 + t;         // over 249856
        if (i < 49152) w_prep_one(Wf2, Wf2b, i);
        else if (i < 98304) w_prep_one(W1, W1b, i - 49152);
        else if (i < 245760) w_prep_one(W2, W2b, i - 98304);
        else {
            // Wf1b: [K=32 pad][128], row 20 = bias, rows 21..31 = 0
            const int idx = i - 245760;             // over 4096
            const int k = idx >> 7, c = idx & 127;
            const float v = (k < NUM_RBF) ? Wf1[k * HIDDEN + c]
                          : (k == NUM_RBF ? bf1[c] : 0.0f);
            const int nt = c >> 4, lr = c & 15;
            const int lh = k >> 3, bb = k & 7;
            Wf1b[((nt * 64) + lh * 16 + lr) * 8 + bb] = f2b(v);
        }
    } else {
        const int i = (b - A_PK - A_W) * 256 + t;
        if (i < N_EDGES) atomicAdd(&counts[ei[i]], 1);  // row 0 = target
    }
}

// ---------------------------------------------------------------------------
// Kernel C: single-block exclusive scan -> cursor
// (after scatter_kernel runs, cursor[i] == row_ptr[i+1])
// ---------------------------------------------------------------------------
#define SCAN_NT 1024
#define SCAN_CHUNK 10
__global__ __launch_bounds__(SCAN_NT) void scan_kernel(
    const int* __restrict__ counts, int* __restrict__ cursor) {
    __shared__ int s[SCAN_NT];
    const int t = threadIdx.x;
    const int base = t * SCAN_CHUNK;
    int local[SCAN_CHUNK];
    int sum = 0;
#pragma unroll
    for (int i = 0; i < SCAN_CHUNK; ++i) {
        const int idx = base + i;
        const int v = (idx < N_NODES) ? counts[idx] : 0;
        local[i] = sum;
        sum += v;
    }
    s[t] = sum;
    __syncthreads();
    for (int d = 1; d < SCAN_NT; d <<= 1) {
        const int v = (t >= d) ? s[t - d] : 0;
        __syncthreads();
        s[t] += v;
        __syncthreads();
    }
    const int excl = (t == 0) ? 0 : s[t - 1];
#pragma unroll
    for (int i = 0; i < SCAN_CHUNK; ++i) {
        const int idx = base + i;
        if (idx < N_NODES) cursor[idx] = excl + local[i];
    }
}

// ---------------------------------------------------------------------------
// Kernel D (fused): blocks [0,313) node MLP (MFMA); [313,938) perm scatter.
// ---------------------------------------------------------------------------
#define D_NODE 313
#define D_SCAT 625

__global__ __launch_bounds__(512) void node_scatter_kernel(
    const float*  __restrict__ q,
    const ushort* __restrict__ W1b, const float* __restrict__ b1,
    const ushort* __restrict__ W2b, const float* __restrict__ b2,
    const int* __restrict__ ei, int* __restrict__ cursor,
    int* __restrict__ perm,
    ushort* __restrict__ x_pack) {          // = src_pack as ushorts

    __shared__ ushort q_s[32 * HIDDEN];   // 8 KB, 256B rows, XOR-swizzled
    __shared__ ushort h_s[32 * H3];       // 24 KB, 768B rows, XOR-swizzled

    const int t = threadIdx.x;

    if (blockIdx.x >= D_NODE) {           // ---- scatter branch ----
        const int i = (blockIdx.x - D_NODE) * 512 + t;
        if (i < N_EDGES) {
            const int tg = ei[i];
            const int pos = atomicAdd(&cursor[tg], 1);
            perm[pos] = i;
        }
        return;
    }

    // ---- node MLP branch ----
    const int n0 = blockIdx.x * 32;
    const int nt = min(32, N_NODES - n0);

    for (int idx = t; idx < 32 * HIDDEN; idx += 512) {
        const int i = idx >> 7, k = idx & 127;
        const float v = (i < nt) ? q[(n0 + i) * HIDDEN + k] : 0.0f;
        const int byte = i * 256 + (((k << 1)) ^ ((i & 7) << 4));
        q_s[byte >> 1] = f2b(v);
    }
    __syncthreads();

    const int wv = t >> 6, lane = t & 63;
    const int lr = lane & 15, lh = lane >> 4;

    // layer 1: [32,128] @ [128,384] -> silu -> h_s
    {
        floatx4 acc[2][3];
#pragma unroll
        for (int m = 0; m < 2; ++m)
#pragma unroll
            for (int n = 0; n < 3; ++n) acc[m][n] = (floatx4){0.f, 0.f, 0.f, 0.f};

#pragma unroll
        for (int kt = 0; kt < 4; ++kt) {
            const int kbyte = kt * 64 + lh * 16;
            const int r0 = lr, r1 = 16 + lr;
            const int b0 = r0 * 256 + (kbyte ^ ((r0 & 7) << 4));
            const int bb1 = r1 * 256 + (kbyte ^ ((r1 & 7) << 4));
            const short8 a0 = *reinterpret_cast<const short8*>(&q_s[b0 >> 1]);
            const short8 a1 = *reinterpret_cast<const short8*>(&q_s[bb1 >> 1]);
#pragma unroll
            for (int n = 0; n < 3; ++n) {
                const int tile = wv * 3 + n;
                const short8 b = *reinterpret_cast<const short8*>(
                    &W1b[(((kt * 24) + tile) * 64 + lane) * 8]);
                acc[0][n] = __builtin_amdgcn_mfma_f32_16x16x32_bf16(
                    a0, b, acc[0][n], 0, 0, 0);
                acc[1][n] = __builtin_amdgcn_mfma_f32_16x16x32_bf16(
                    a1, b, acc[1][n], 0, 0, 0);
            }
        }
#pragma unroll
        for (int n = 0; n < 3; ++n) {
            const int c = (wv * 3 + n) * 16 + lr;
            const float bb = b1[c];
#pragma unroll
            for (int m = 0; m < 2; ++m) {
#pragma unroll
                for (int r = 0; r < 4; ++r) {
                    const int row = m * 16 + lh * 4 + r;
                    const float v = acc[m][n][r] + bb;
                    const float s = v / (1.0f + __expf(-v));
                    const int byte = row * 768 + (((c << 1)) ^ ((row & 7) << 4));
                    h_s[byte >> 1] = f2b(s);
                }
            }
        }
    }
    __syncthreads();

    // layer 2: [32,384] @ [384,384] -> x slots of src_pack
    {
        floatx4 acc[2][3];
#pragma unroll
        for (int m = 0; m < 2; ++m)
#pragma unroll
            for (int n = 0; n < 3; ++n) acc[m][n] = (floatx4){0.f, 0.f, 0.f, 0.f};

#pragma unroll
        for (int kt = 0; kt < 12; ++kt) {
            const int kbyte = kt * 64 + lh * 16;
            const int r0 = lr, r1 = 16 + lr;
            const int b0 = r0 * 768 + (kbyte ^ ((r0 & 7) << 4));
            const int bb1 = r1 * 768 + (kbyte ^ ((r1 & 7) << 4));
            const short8 a0 = *reinterpret_cast<const short8*>(&h_s[b0 >> 1]);
            const short8 a1 = *reinterpret_cast<const short8*>(&h_s[bb1 >> 1]);
#pragma unroll
            for (int n = 0; n < 3; ++n) {
                const int tile = wv * 3 + n;
                const short8 b = *reinterpret_cast<const short8*>(
                    &W2b[(((kt * 24) + tile) * 64 + lane) * 8]);
                acc[0][n] = __builtin_amdgcn_mfma_f32_16x16x32_bf16(
                    a0, b, acc[0][n], 0, 0, 0);
                acc[1][n] = __builtin_amdgcn_mfma_f32_16x16x32_bf16(
                    a1, b, acc[1][n], 0, 0, 0);
            }
        }
#pragma unroll
        for (int n = 0; n < 3; ++n) {
            const int c  = (wv * 3 + n) * 16 + lr;
            const int cc = c & 127, p = c >> 7;          // p=0:xq 1:xr 2:xm
            const float bb = b2[c];
#pragma unroll
            for (int m = 0; m < 2; ++m) {
#pragma unroll
                for (int r = 0; r < 4; ++r) {
                    const int row = m * 16 + lh * 4 + r;
                    if (row < nt)
                        x_pack[((size_t)(n0 + row) * 128 + cc) * 8 + p] =
                            f2b(acc[m][n][r] + bb);
                }
            }
        }
    }
}

// ---------------------------------------------------------------------------
// Kernel E: node-centric fused edge kernel. Block owns NPB=4 target nodes and
// ALL their edges (CSR). Zero global atomics: LDS f32 accumulator, plain
// stores in the epilogue (out = q/mu + acc).
// ---------------------------------------------------------------------------
__global__ __launch_bounds__(512) void edge_kernel(
    const ushort* __restrict__ src_pack,  // [N][128][8] bf16 (xq,xr,xm,_,m0,m1,m2,_)
    const float*  __restrict__ q,         // [N,128]
    const float*  __restrict__ mu,        // [N,3,128]
    const int*    __restrict__ ei,
    const int*    __restrict__ perm,      // [E] edge ids sorted by target
    const int*    __restrict__ row_end,   // cursor after scatter: row_ptr[i+1]
    const float*  __restrict__ rbf,
    const float*  __restrict__ uv,
    const float*  __restrict__ cut,
    const ushort* __restrict__ Wf1b,      // [32pad][128] frag-linear (bias-folded)
    const ushort* __restrict__ Wf2b,
    const float*  __restrict__ bf2,
    float* __restrict__ out_q,            // [N,128]
    float* __restrict__ out_mu) {         // [N,3,128]

    __shared__ ushort rbf_s[32 * RBF_STRIDE];   // 2.5 KB bf16, K padded to 32
    __shared__ ushort h1_s[32 * HIDDEN];        // 8 KB, XOR-swizzled
    __shared__ ushort f_pack[32 * FP_STRIDE];   // 33 KB
    __shared__ float  acc_s[NPB][512];          // 8 KB f32 accumulator
    __shared__ int    eid_s[32], src_s[32], tgt_s[32];
    __shared__ float  uv_s[32][3], cut_s[32];

    const int n0 = blockIdx.x * NPB;
    const int t  = threadIdx.x;

    const int e_begin = (n0 == 0) ? 0 : row_end[n0 - 1];
    const int e_end   = row_end[n0 + NPB - 1];

    // zero accumulator
#pragma unroll
    for (int k = 0; k < NPB; ++k) acc_s[k][t] = 0.0f;

    const int wv   = t >> 6;
    const int lane = t & 63;
    const int lr   = lane & 15;
    const int lh   = lane >> 4;

    for (int base = e_begin; base < e_end; base += 32) {
        __syncthreads();   // acc zero visible / prev chunk message done

        // ---- stage 32 edges (pad with cut=0 => zero contribution) ----
        if (t < 32) {
            const int e = base + t;
            const bool valid = (e < e_end);
            const int eid = perm[valid ? e : e_begin];
            eid_s[t] = eid;
            tgt_s[t] = valid ? ei[eid] : n0;
            src_s[t] = ei[N_EDGES + eid];
            cut_s[t] = valid ? cut[eid] : 0.0f;
            uv_s[t][0] = uv[eid * 3 + 0];
            uv_s[t][1] = uv[eid * 3 + 1];
            uv_s[t][2] = uv[eid * 3 + 2];
        }
        __syncthreads();
        for (int idx = t; idx < 32 * RBF_STRIDE; idx += 512) {
            const int i = idx / RBF_STRIDE, k = idx % RBF_STRIDE;
            const float v = (k < NUM_RBF) ? rbf[eid_s[i] * NUM_RBF + k]
                          : (k == NUM_RBF ? 1.0f : 0.0f);
            rbf_s[idx] = f2b(v);
        }
        __syncthreads();

        // ---- filter layer 1 via MFMA -> silu -> h1_s ----
        {
            floatx4 acc1[2];
            acc1[0] = (floatx4){0.f, 0.f, 0.f, 0.f};
            acc1[1] = (floatx4){0.f, 0.f, 0.f, 0.f};
            const short8 bfrag = *reinterpret_cast<const short8*>(
                &Wf1b[(wv * 64 + lane) * 8]);
#pragma unroll
            for (int m = 0; m < 2; ++m) {
                const short8 a = *reinterpret_cast<const short8*>(
                    &rbf_s[(m * 16 + lr) * RBF_STRIDE + lh * 8]);
                acc1[m] = __builtin_amdgcn_mfma_f32_16x16x32_bf16(
                    a, bfrag, acc1[m], 0, 0, 0);
            }
#pragma unroll
            for (int m = 0; m < 2; ++m) {
#pragma unroll
                for (int r = 0; r < 4; ++r) {
                    const int row = m * 16 + lh * 4 + r;
                    const int c   = wv * 16 + lr;
                    const float v = acc1[m][r];           // bias folded in
                    const float s = v / (1.0f + __expf(-v));
                    const int byte = row * 256 + (((c << 1)) ^ ((row & 7) << 4));
                    h1_s[byte >> 1] = f2b(s);
                }
            }
        }
        __syncthreads();

        // ---- filter layer 2 via MFMA -> f_pack ----
        {
            floatx4 acc[2][3];
#pragma unroll
            for (int m = 0; m < 2; ++m)
#pragma unroll
                for (int n = 0; n < 3; ++n) acc[m][n] = (floatx4){0.f, 0.f, 0.f, 0.f};

#pragma unroll
            for (int kt = 0; kt < 4; ++kt) {
                const int kbyte = kt * 64 + lh * 16;
                const int r0 = lr, r1 = 16 + lr;
                const int b0 = r0 * 256 + (kbyte ^ ((r0 & 7) << 4));
                const int bb1 = r1 * 256 + (kbyte ^ ((r1 & 7) << 4));
                const short8 a0 = *reinterpret_cast<const short8*>(&h1_s[b0 >> 1]);
                const short8 a1 = *reinterpret_cast<const short8*>(&h1_s[bb1 >> 1]);
#pragma unroll
                for (int n = 0; n < 3; ++n) {
                    const int tile = wv * 3 + n;
                    const short8 b = *reinterpret_cast<const short8*>(
                        &Wf2b[(((kt * 24) + tile) * 64 + lane) * 8]);
                    acc[0][n] = __builtin_amdgcn_mfma_f32_16x16x32_bf16(
                        a0, b, acc[0][n], 0, 0, 0);
                    acc[1][n] = __builtin_amdgcn_mfma_f32_16x16x32_bf16(
                        a1, b, acc[1][n], 0, 0, 0);
                }
            }
#pragma unroll
            for (int n = 0; n < 3; ++n) {
                const int c  = (wv * 3 + n) * 16 + lr;
                const int cc = c & 127, p = c >> 7;
                const float bb = bf2[c];
#pragma unroll
                for (int m = 0; m < 2; ++m) {
#pragma unroll
                    for (int r = 0; r < 4; ++r) {
                        const int row = m * 16 + lh * 4 + r;
                        f_pack[row * FP_STRIDE + cc * 4 + p] =
                            f2b((acc[m][n][r] + bb) * cut_s[row]);
                    }
                }
            }
        }
        __syncthreads();

        // ---- message: 128 ch x 4 subtiles of 8 edges, LDS-acc flush ----
        {
            const int c   = t & 127;
            const int sub = t >> 7;
            const ushort8v* sp8 = (const ushort8v*)src_pack;

            ushort8v sp[8];
            ushort4  fpv[8];
#pragma unroll
            for (int k = 0; k < 8; ++k) {
                const int i = sub * 8 + k;
                sp[k]  = sp8[(size_t)src_s[i] * 128 + c];
                fpv[k] = *reinterpret_cast<const ushort4*>(
                    &f_pack[i * FP_STRIDE + c * 4]);
            }

            float aq = 0.f, a0 = 0.f, a1 = 0.f, a2 = 0.f;
            int cur = tgt_s[sub * 8];
#pragma unroll
            for (int k = 0; k < 8; ++k) {
                const int i = sub * 8 + k;
                const int tg = tgt_s[i];
                if (tg != cur) {                // subtile-uniform branch
                    atomicAdd(&acc_s[cur - n0][c], aq);
                    atomicAdd(&acc_s[cur - n0][128 + c], a0);
                    atomicAdd(&acc_s[cur - n0][256 + c], a1);
                    atomicAdd(&acc_s[cur - n0][384 + c], a2);
                    aq = a0 = a1 = a2 = 0.f;
                    cur = tg;
                }
                const float xrr = b2f(sp[k][1]) * b2f(fpv[k].y);
                const float xmm = b2f(sp[k][2]) * b2f(fpv[k].z);
                aq = fmaf(b2f(sp[k][0]), b2f(fpv[k].x), aq);
                a0 = fmaf(uv_s[i][0], xrr, fmaf(b2f(sp[k][4]), xmm, a0));
                a1 = fmaf(uv_s[i][1], xrr, fmaf(b2f(sp[k][5]), xmm, a1));
                a2 = fmaf(uv_s[i][2], xrr, fmaf(b2f(sp[k][6]), xmm, a2));
            }
            atomicAdd(&acc_s[cur - n0][c], aq);
            atomicAdd(&acc_s[cur - n0][128 + c], a0);
            atomicAdd(&acc_s[cur - n0][256 + c], a1);
            atomicAdd(&acc_s[cur - n0][384 + c], a2);
        }
    }
    __syncthreads();

    // ---- epilogue: out = q/mu + acc, plain coalesced stores ----
    {
        const int part = t >> 7, c = t & 127;
#pragma unroll
        for (int k = 0; k < NPB; ++k) {
            const int node = n0 + k;
            const float a = acc_s[k][t];
            if (part == 0)
                out_q[node * HIDDEN + c] = q[node * HIDDEN + c] + a;
            else
                out_mu[(node * 3 + part - 1) * HIDDEN + c] =
                    mu[(node * 3 + part - 1) * HIDDEN + c] + a;
        }
    }
}

// ---------------------------------------------------------------------------
extern "C" void kernel_launch(void* const* d_in, const int* in_sizes, int n_in,
                              void* d_out, int out_size, void* d_ws, size_t ws_size,
                              hipStream_t stream) {
    const float* q   = (const float*)d_in[0];
    const float* mu  = (const float*)d_in[1];
    const int*   ei  = (const int*)  d_in[2];
    const float* rbf = (const float*)d_in[3];
    const float* uv  = (const float*)d_in[4];
    const float* cut = (const float*)d_in[5];
    const float* W1  = (const float*)d_in[6];
    const float* b1  = (const float*)d_in[7];
    const float* W2  = (const float*)d_in[8];
    const float* b2  = (const float*)d_in[9];
    const float* Wf1 = (const float*)d_in[10];
    const float* bf1 = (const float*)d_in[11];
    const float* Wf2 = (const float*)d_in[12];
    const float* bf2 = (const float*)d_in[13];

    float* out    = (float*)d_out;
    float* out_q  = out;
    float* out_mu = out + N_NODES * HIDDEN;

    // ws layout (bytes), total ~22.34 MB (same footprint as R6/R7, proven)
    char* ws = (char*)d_ws;
    size_t off = 0;
    ushort* Wf2b     = (ushort*)(ws + off); off += 98304;
    ushort* W1b      = (ushort*)(ws + off); off += 98304;
    ushort* W2b      = (ushort*)(ws + off); off += 294912;
    ushort* Wf1b     = (ushort*)(ws + off); off += 8192;
    ushort* src_pack = (ushort*)(ws + off); off += (size_t)N_NODES * 128 * 8 * 2;
    int*    perm     = (int*)   (ws + off); off += (size_t)N_EDGES * 4;
    int*    counts   = (int*)   (ws + off); off += (size_t)N_NODES * 4 + 960;
    int*    cursor   = (int*)   (ws + off); off += (size_t)N_NODES * 4 + 960;
    (void)ws_size;

    hipMemsetAsync(counts, 0, (size_t)N_NODES * 4, stream);

    // A: fused prep (mu pack + weight repack + histogram)
    prep_kernel<<<A_PK + A_W + A_H, 256, 0, stream>>>(
        mu, Wf2, W1, W2, Wf1, bf1, ei,
        (ushort4*)src_pack, Wf2b, W1b, W2b, Wf1b, counts);

    // C: exclusive scan -> cursor (becomes row_end after scatter)
    scan_kernel<<<1, SCAN_NT, 0, stream>>>(counts, cursor);

    // D: node MLP + perm scatter
    node_scatter_kernel<<<D_NODE + D_SCAT, 512, 0, stream>>>(
        q, W1b, b1, W2b, b2, ei, cursor, perm, src_pack);

    // E: node-centric edge kernel (no global atomics)
    edge_kernel<<<N_NODES / NPB, 512, 0, stream>>>(
        src_pack, q, mu, ei, perm, cursor, rbf, uv, cut,
        Wf1b, Wf2b, bf2, out_q, out_mu);
}

// Round 9
// 307.634 us; speedup vs baseline: 1.8143x; 1.8143x over previous
//
#include <hip/hip_runtime.h>
#include <math.h>

#define N_NODES 10000
#define N_EDGES 320000
#define HIDDEN  128
#define NUM_RBF 20
#define H3      384   // 3*HIDDEN
#define FP_STRIDE 516 // f_pack row stride in ushorts (1032B)
#define RBF_STRIDE 40 // rbf_s row stride in ushorts (80B)
#define REC_F   24    // floats per sorted edge record (96B)

typedef __attribute__((ext_vector_type(8))) short short8;
typedef __attribute__((ext_vector_type(8))) unsigned short ushort8v;
typedef __attribute__((ext_vector_type(4))) float floatx4;

__device__ __forceinline__ float b2f(ushort u) {
    unsigned v = ((unsigned)u) << 16; float f; __builtin_memcpy(&f, &v, 4); return f;
}
__device__ __forceinline__ ushort f2b(float f) {   // RNE f32 -> bf16
    unsigned x; __builtin_memcpy(&x, &f, 4);
    return (ushort)((x + 0x7fffu + ((x >> 16) & 1u)) >> 16);
}

// ---------------------------------------------------------------------------
// Kernel A (fused prep), grid-split:
//   seg0: out[0:NQ)  = q                    (1250 blocks)
//   seg1: out[NQ:..) = mu                   (3750 blocks)
//   seg2: src_pack mu slots (bf16)          (5000 blocks)
//   seg3: w_prep Wf2/W1/W2 + Wf1b(bias-fold)(976 blocks)
//   seg4: histogram of targets              (1250 blocks; counts pre-memset)
// ---------------------------------------------------------------------------
#define A_Q  1250
#define A_MU 3750
#define A_PK 5000
#define A_W  976
#define A_H  1250

__device__ __forceinline__ void w_prep_one(const float* __restrict__ W,
                                           ushort* __restrict__ Wb, int idx) {
    const int k = idx / H3, j = idx % H3;
    const int kt = k >> 5, r = k & 31;
    const int hi = r >> 3, b = r & 7;
    const int nt = j >> 4, jj = j & 15;
    const int lane = hi * 16 + jj;
    Wb[(((kt * 24 + nt) * 64) + lane) * 8 + b] = f2b(W[k * H3 + j]);
}

__global__ __launch_bounds__(256) void prep_kernel(
    const float4* __restrict__ q4, const float4* __restrict__ mu4,
    const float* __restrict__ mu,
    const float* __restrict__ Wf2, const float* __restrict__ W1,
    const float* __restrict__ W2,
    const float* __restrict__ Wf1, const float* __restrict__ bf1,
    const int* __restrict__ ei,
    float4* __restrict__ out4, ushort4* __restrict__ src_pack,
    ushort* __restrict__ Wf2b, ushort* __restrict__ W1b,
    ushort* __restrict__ W2b, ushort* __restrict__ Wf1b,
    int* __restrict__ counts) {

    const int b = blockIdx.x, t = threadIdx.x;
    if (b < A_Q) {
        const int i = b * 256 + t;
        if (i < N_NODES * HIDDEN / 4) out4[i] = q4[i];
    } else if (b < A_Q + A_MU) {
        const int i = (b - A_Q) * 256 + t;
        if (i < N_NODES * 3 * HIDDEN / 4)
            out4[N_NODES * HIDDEN / 4 + i] = mu4[i];
    } else if (b < A_Q + A_MU + A_PK) {
        const int i = (b - A_Q - A_MU) * 256 + t;   // over N*128
        if (i < N_NODES * HIDDEN) {
            const int n = i >> 7, c = i & 127;
            ushort4 v;
            v.x = f2b(mu[(n * 3 + 0) * HIDDEN + c]);
            v.y = f2b(mu[(n * 3 + 1) * HIDDEN + c]);
            v.z = f2b(mu[(n * 3 + 2) * HIDDEN + c]);
            v.w = 0;
            src_pack[(size_t)i * 2 + 1] = v;        // slot 1 of 16B record
        }
    } else if (b < A_Q + A_MU + A_PK + A_W) {
        const int i = (b - A_Q - A_MU - A_PK) * 256 + t;  // over 249856
        if (i < 49152) w_prep_one(Wf2, Wf2b, i);
        else if (i < 98304) w_prep_one(W1, W1b, i - 49152);
        else if (i < 245760) w_prep_one(W2, W2b, i - 98304);
        else {
            // Wf1b: [K=32 pad][128], row 20 = bias, rows 21..31 = 0
            const int idx = i - 245760;             // over 4096
            const int k = idx >> 7, c = idx & 127;
            const float v = (k < NUM_RBF) ? Wf1[k * HIDDEN + c]
                          : (k == NUM_RBF ? bf1[c] : 0.0f);
            const int nt = c >> 4, lr = c & 15;
            const int lh = k >> 3, bb = k & 7;
            Wf1b[((nt * 64) + lh * 16 + lr) * 8 + bb] = f2b(v);
        }
    } else {
        const int i = (b - A_Q - A_MU - A_PK - A_W) * 256 + t;
        if (i < N_EDGES) atomicAdd(&counts[ei[i]], 1);  // row 0 = target
    }
}

// ---------------------------------------------------------------------------
// Kernel C: single-block exclusive scan -> cursor
// ---------------------------------------------------------------------------
#define SCAN_NT 1024
#define SCAN_CHUNK 10
__global__ __launch_bounds__(SCAN_NT) void scan_kernel(
    const int* __restrict__ counts, int* __restrict__ cursor) {
    __shared__ int s[SCAN_NT];
    const int t = threadIdx.x;
    const int base = t * SCAN_CHUNK;
    int local[SCAN_CHUNK];
    int sum = 0;
#pragma unroll
    for (int i = 0; i < SCAN_CHUNK; ++i) {
        const int idx = base + i;
        const int v = (idx < N_NODES) ? counts[idx] : 0;
        local[i] = sum;
        sum += v;
    }
    s[t] = sum;
    __syncthreads();
    for (int d = 1; d < SCAN_NT; d <<= 1) {
        const int v = (t >= d) ? s[t - d] : 0;
        __syncthreads();
        s[t] += v;
        __syncthreads();
    }
    const int excl = (t == 0) ? 0 : s[t - 1];
#pragma unroll
    for (int i = 0; i < SCAN_CHUNK; ++i) {
        const int idx = base + i;
        if (idx < N_NODES) cursor[idx] = excl + local[i];
    }
}

// ---------------------------------------------------------------------------
// Kernel D (fused): blocks [0,313) node MLP (MFMA);
// blocks [313,938): sort-scatter — write the full 96B edge record at its
// sorted position (physical permutation; no perm[] indirection downstream).
// ---------------------------------------------------------------------------
#define D_NODE 313
#define D_SCAT 625

__global__ __launch_bounds__(512) void node_scatter_kernel(
    const float*  __restrict__ q,
    const ushort* __restrict__ W1b, const float* __restrict__ b1,
    const ushort* __restrict__ W2b, const float* __restrict__ b2,
    const int* __restrict__ ei, int* __restrict__ cursor,
    const float* __restrict__ rbf, const float* __restrict__ uv,
    const float* __restrict__ cut,
    float* __restrict__ edata,              // [E][REC_F] sorted records
    ushort* __restrict__ x_pack) {          // = src_pack as ushorts

    __shared__ ushort q_s[32 * HIDDEN];   // 8 KB, 256B rows, XOR-swizzled
    __shared__ ushort h_s[32 * H3];       // 24 KB, 768B rows, XOR-swizzled

    const int t = threadIdx.x;

    if (blockIdx.x >= D_NODE) {           // ---- sort-scatter branch ----
        const int i = (blockIdx.x - D_NODE) * 512 + t;
        if (i < N_EDGES) {
            const int tg = ei[i];
            const int sr = ei[N_EDGES + i];
            const int pos = atomicAdd(&cursor[tg], 1);
            float* rec = edata + (size_t)pos * REC_F;
            rec[0] = __int_as_float(sr);
            rec[1] = __int_as_float(tg);
            rec[2] = cut[i];
            rec[3] = uv[i * 3 + 0];
            rec[4] = uv[i * 3 + 1];
            rec[5] = uv[i * 3 + 2];
            // rbf as bf16 pairs: slots 0..19 = rbf, 20 = 1.0 (bias), 21..31 = 0
            unsigned* rb = (unsigned*)(rec + 8);
#pragma unroll
            for (int k = 0; k < 10; ++k) {
                const unsigned lo = f2b(rbf[i * NUM_RBF + 2 * k]);
                const unsigned hi = f2b(rbf[i * NUM_RBF + 2 * k + 1]);
                rb[k] = lo | (hi << 16);
            }
            rb[10] = 0x3f80u;       // {1.0bf16, 0}
            rb[11] = 0; rb[12] = 0; rb[13] = 0; rb[14] = 0; rb[15] = 0;
        }
        return;
    }

    // ---- node MLP branch ----
    const int n0 = blockIdx.x * 32;
    const int nt = min(32, N_NODES - n0);

    for (int idx = t; idx < 32 * HIDDEN; idx += 512) {
        const int i = idx >> 7, k = idx & 127;
        const float v = (i < nt) ? q[(n0 + i) * HIDDEN + k] : 0.0f;
        const int byte = i * 256 + (((k << 1)) ^ ((i & 7) << 4));
        q_s[byte >> 1] = f2b(v);
    }
    __syncthreads();

    const int wv = t >> 6, lane = t & 63;
    const int lr = lane & 15, lh = lane >> 4;

    // layer 1: [32,128] @ [128,384] -> silu -> h_s
    {
        floatx4 acc[2][3];
#pragma unroll
        for (int m = 0; m < 2; ++m)
#pragma unroll
            for (int n = 0; n < 3; ++n) acc[m][n] = (floatx4){0.f, 0.f, 0.f, 0.f};

#pragma unroll
        for (int kt = 0; kt < 4; ++kt) {
            const int kbyte = kt * 64 + lh * 16;
            const int r0 = lr, r1 = 16 + lr;
            const int b0 = r0 * 256 + (kbyte ^ ((r0 & 7) << 4));
            const int bb1 = r1 * 256 + (kbyte ^ ((r1 & 7) << 4));
            const short8 a0 = *reinterpret_cast<const short8*>(&q_s[b0 >> 1]);
            const short8 a1 = *reinterpret_cast<const short8*>(&q_s[bb1 >> 1]);
#pragma unroll
            for (int n = 0; n < 3; ++n) {
                const int tile = wv * 3 + n;
                const short8 b = *reinterpret_cast<const short8*>(
                    &W1b[(((kt * 24) + tile) * 64 + lane) * 8]);
                acc[0][n] = __builtin_amdgcn_mfma_f32_16x16x32_bf16(
                    a0, b, acc[0][n], 0, 0, 0);
                acc[1][n] = __builtin_amdgcn_mfma_f32_16x16x32_bf16(
                    a1, b, acc[1][n], 0, 0, 0);
            }
        }
#pragma unroll
        for (int n = 0; n < 3; ++n) {
            const int c = (wv * 3 + n) * 16 + lr;
            const float bb = b1[c];
#pragma unroll
            for (int m = 0; m < 2; ++m) {
#pragma unroll
                for (int r = 0; r < 4; ++r) {
                    const int row = m * 16 + lh * 4 + r;
                    const float v = acc[m][n][r] + bb;
                    const float s = v / (1.0f + __expf(-v));
                    const int byte = row * 768 + (((c << 1)) ^ ((row & 7) << 4));
                    h_s[byte >> 1] = f2b(s);
                }
            }
        }
    }
    __syncthreads();

    // layer 2: [32,384] @ [384,384] -> x slots of src_pack
    {
        floatx4 acc[2][3];
#pragma unroll
        for (int m = 0; m < 2; ++m)
#pragma unroll
            for (int n = 0; n < 3; ++n) acc[m][n] = (floatx4){0.f, 0.f, 0.f, 0.f};

#pragma unroll
        for (int kt = 0; kt < 12; ++kt) {
            const int kbyte = kt * 64 + lh * 16;
            const int r0 = lr, r1 = 16 + lr;
            const int b0 = r0 * 768 + (kbyte ^ ((r0 & 7) << 4));
            const int bb1 = r1 * 768 + (kbyte ^ ((r1 & 7) << 4));
            const short8 a0 = *reinterpret_cast<const short8*>(&h_s[b0 >> 1]);
            const short8 a1 = *reinterpret_cast<const short8*>(&h_s[bb1 >> 1]);
#pragma unroll
            for (int n = 0; n < 3; ++n) {
                const int tile = wv * 3 + n;
                const short8 b = *reinterpret_cast<const short8*>(
                    &W2b[(((kt * 24) + tile) * 64 + lane) * 8]);
                acc[0][n] = __builtin_amdgcn_mfma_f32_16x16x32_bf16(
                    a0, b, acc[0][n], 0, 0, 0);
                acc[1][n] = __builtin_amdgcn_mfma_f32_16x16x32_bf16(
                    a1, b, acc[1][n], 0, 0, 0);
            }
        }
#pragma unroll
        for (int n = 0; n < 3; ++n) {
            const int c  = (wv * 3 + n) * 16 + lr;
            const int cc = c & 127, p = c >> 7;          // p=0:xq 1:xr 2:xm
            const float bb = b2[c];
#pragma unroll
            for (int m = 0; m < 2; ++m) {
#pragma unroll
                for (int r = 0; r < 4; ++r) {
                    const int row = m * 16 + lh * 4 + r;
                    if (row < nt)
                        x_pack[((size_t)(n0 + row) * 128 + cc) * 8 + p] =
                            f2b(acc[m][n][r] + bb);
                }
            }
        }
    }
}

// ---------------------------------------------------------------------------
// Kernel E: fused edge filter MLP (full MFMA) + sorted segment reduction.
// 512 threads, 32 sorted edges/block from edata records (coalesced staging).
// XCD-chunked block swizzle: each XCD owns a contiguous slice of the sorted
// edge list -> its out-lines stay in that XCD's L2 (atomic locality).
// ---------------------------------------------------------------------------
__global__ __launch_bounds__(512) void edge_kernel(
    const ushort* __restrict__ src_pack,  // [N][128][8] bf16 (xq,xr,xm,_,m0,m1,m2,_)
    const float*  __restrict__ edata,     // [E][REC_F] sorted records
    const ushort* __restrict__ Wf1b,      // [32pad][128] frag-linear (bias-folded)
    const ushort* __restrict__ Wf2b,
    const float*  __restrict__ bf2,
    float* __restrict__ out_q,            // [N,128]   pre-init to q
    float* __restrict__ out_mu) {         // [N,3,128] pre-init to mu

    __shared__ float  edata_s[32 * REC_F];      // 3 KB raw records
    __shared__ ushort rbf_s[32 * RBF_STRIDE];   // 2.5 KB bf16, K padded to 32
    __shared__ ushort h1_s[32 * HIDDEN];        // 8 KB, XOR-swizzled
    __shared__ ushort f_pack[32 * FP_STRIDE];   // 33 KB
    __shared__ int    src_s[32], tgt_s[32];
    __shared__ float  uv_s[32][3], cut_s[32];

    // bijective XCD-chunked swizzle (10000 % 8 == 0)
    const int bid   = blockIdx.x;
    const int chunk = (bid & 7) * 1250 + (bid >> 3);
    const int t     = threadIdx.x;

    // ---- stage 32 records, coalesced ----
    for (int j = t; j < 32 * REC_F; j += 512)
        edata_s[j] = edata[(size_t)chunk * 32 * REC_F + j];
    __syncthreads();
    if (t < 32) {
        src_s[t] = __float_as_int(edata_s[t * REC_F + 0]);
        tgt_s[t] = __float_as_int(edata_s[t * REC_F + 1]);
        cut_s[t] = edata_s[t * REC_F + 2];
        uv_s[t][0] = edata_s[t * REC_F + 3];
        uv_s[t][1] = edata_s[t * REC_F + 4];
        uv_s[t][2] = edata_s[t * REC_F + 5];
    }
    {
        const ushort* eu = (const ushort*)edata_s;
        for (int idx = t; idx < 32 * 32; idx += 512) {
            const int i = idx >> 5, k = idx & 31;
            rbf_s[i * RBF_STRIDE + k] = eu[i * (REC_F * 2) + 16 + k];
        }
    }
    __syncthreads();

    const int wv   = t >> 6;
    const int lane = t & 63;
    const int lr   = lane & 15;
    const int lh   = lane >> 4;

    // ---- filter layer 1 via MFMA: [32,32pad] @ [32pad,128] -> silu -> h1_s ----
    {
        floatx4 acc1[2];
        acc1[0] = (floatx4){0.f, 0.f, 0.f, 0.f};
        acc1[1] = (floatx4){0.f, 0.f, 0.f, 0.f};
        const short8 bfrag = *reinterpret_cast<const short8*>(
            &Wf1b[(wv * 64 + lane) * 8]);
#pragma unroll
        for (int m = 0; m < 2; ++m) {
            const short8 a = *reinterpret_cast<const short8*>(
                &rbf_s[(m * 16 + lr) * RBF_STRIDE + lh * 8]);
            acc1[m] = __builtin_amdgcn_mfma_f32_16x16x32_bf16(
                a, bfrag, acc1[m], 0, 0, 0);
        }
#pragma unroll
        for (int m = 0; m < 2; ++m) {
#pragma unroll
            for (int r = 0; r < 4; ++r) {
                const int row = m * 16 + lh * 4 + r;
                const int c   = wv * 16 + lr;
                const float v = acc1[m][r];               // bias folded in
                const float s = v / (1.0f + __expf(-v));
                const int byte = row * 256 + (((c << 1)) ^ ((row & 7) << 4));
                h1_s[byte >> 1] = f2b(s);
            }
        }
    }
    __syncthreads();

    // ---- filter layer 2 via MFMA: [32,128] @ [128,384] -> f_pack ----
    {
        floatx4 acc[2][3];
#pragma unroll
        for (int m = 0; m < 2; ++m)
#pragma unroll
            for (int n = 0; n < 3; ++n) acc[m][n] = (floatx4){0.f, 0.f, 0.f, 0.f};

#pragma unroll
        for (int kt = 0; kt < 4; ++kt) {
            const int kbyte = kt * 64 + lh * 16;
            const int r0 = lr, r1 = 16 + lr;
            const int b0 = r0 * 256 + (kbyte ^ ((r0 & 7) << 4));
            const int bb1 = r1 * 256 + (kbyte ^ ((r1 & 7) << 4));
            const short8 a0 = *reinterpret_cast<const short8*>(&h1_s[b0 >> 1]);
            const short8 a1 = *reinterpret_cast<const short8*>(&h1_s[bb1 >> 1]);
#pragma unroll
            for (int n = 0; n < 3; ++n) {
                const int tile = wv * 3 + n;
                const short8 b = *reinterpret_cast<const short8*>(
                    &Wf2b[(((kt * 24) + tile) * 64 + lane) * 8]);
                acc[0][n] = __builtin_amdgcn_mfma_f32_16x16x32_bf16(
                    a0, b, acc[0][n], 0, 0, 0);
                acc[1][n] = __builtin_amdgcn_mfma_f32_16x16x32_bf16(
                    a1, b, acc[1][n], 0, 0, 0);
            }
        }

#pragma unroll
        for (int n = 0; n < 3; ++n) {
            const int c  = (wv * 3 + n) * 16 + lr;
            const int cc = c & 127, p = c >> 7;
            const float bb = bf2[c];
#pragma unroll
            for (int m = 0; m < 2; ++m) {
#pragma unroll
                for (int r = 0; r < 4; ++r) {
                    const int row = m * 16 + lh * 4 + r;
                    f_pack[row * FP_STRIDE + cc * 4 + p] =
                        f2b((acc[m][n][r] + bb) * cut_s[row]);
                }
            }
        }
    }
    __syncthreads();

    // ---- message phase: 8-deep prefetch then compute ----
    {
        const int c   = t & 127;
        const int sub = t >> 7;
        const ushort8v* sp8 = (const ushort8v*)src_pack;

        ushort8v sp[8];
        ushort4  fpv[8];
#pragma unroll
        for (int k = 0; k < 8; ++k) {
            const int i = sub * 8 + k;
            sp[k]  = sp8[(size_t)src_s[i] * 128 + c];
            fpv[k] = *reinterpret_cast<const ushort4*>(
                &f_pack[i * FP_STRIDE + c * 4]);
        }

        float aq = 0.f, a0 = 0.f, a1 = 0.f, a2 = 0.f;
        int cur = tgt_s[sub * 8];
#pragma unroll
        for (int k = 0; k < 8; ++k) {
            const int i = sub * 8 + k;
            const int tg = tgt_s[i];
            if (tg != cur) {                    // subtile-uniform branch
                atomicAdd(&out_q[cur * HIDDEN + c], aq);
                atomicAdd(&out_mu[(cur * 3 + 0) * HIDDEN + c], a0);
                atomicAdd(&out_mu[(cur * 3 + 1) * HIDDEN + c], a1);
                atomicAdd(&out_mu[(cur * 3 + 2) * HIDDEN + c], a2);
                aq = a0 = a1 = a2 = 0.f;
                cur = tg;
            }
            const float xrr = b2f(sp[k][1]) * b2f(fpv[k].y);
            const float xmm = b2f(sp[k][2]) * b2f(fpv[k].z);
            aq = fmaf(b2f(sp[k][0]), b2f(fpv[k].x), aq);
            a0 = fmaf(uv_s[i][0], xrr, fmaf(b2f(sp[k][4]), xmm, a0));
            a1 = fmaf(uv_s[i][1], xrr, fmaf(b2f(sp[k][5]), xmm, a1));
            a2 = fmaf(uv_s[i][2], xrr, fmaf(b2f(sp[k][6]), xmm, a2));
        }
        atomicAdd(&out_q[cur * HIDDEN + c], aq);
        atomicAdd(&out_mu[(cur * 3 + 0) * HIDDEN + c], a0);
        atomicAdd(&out_mu[(cur * 3 + 1) * HIDDEN + c], a1);
        atomicAdd(&out_mu[(cur * 3 + 2) * HIDDEN + c], a2);
    }
}

// ---------------------------------------------------------------------------
extern "C" void kernel_launch(void* const* d_in, const int* in_sizes, int n_in,
                              void* d_out, int out_size, void* d_ws, size_t ws_size,
                              hipStream_t stream) {
    const float* q   = (const float*)d_in[0];
    const float* mu  = (const float*)d_in[1];
    const int*   ei  = (const int*)  d_in[2];
    const float* rbf = (const float*)d_in[3];
    const float* uv  = (const float*)d_in[4];
    const float* cut = (const float*)d_in[5];
    const float* W1  = (const float*)d_in[6];
    const float* b1  = (const float*)d_in[7];
    const float* W2  = (const float*)d_in[8];
    const float* b2  = (const float*)d_in[9];
    const float* Wf1 = (const float*)d_in[10];
    const float* bf1 = (const float*)d_in[11];
    const float* Wf2 = (const float*)d_in[12];
    const float* bf2 = (const float*)d_in[13];

    float* out    = (float*)d_out;
    float* out_q  = out;
    float* out_mu = out + N_NODES * HIDDEN;

    // ws layout (bytes), total ~51.8 MB
    char* ws = (char*)d_ws;
    size_t off = 0;
    ushort* Wf2b     = (ushort*)(ws + off); off += 98304;
    ushort* W1b      = (ushort*)(ws + off); off += 98304;
    ushort* W2b      = (ushort*)(ws + off); off += 294912;
    ushort* Wf1b     = (ushort*)(ws + off); off += 8192;
    ushort* src_pack = (ushort*)(ws + off); off += (size_t)N_NODES * 128 * 8 * 2;
    float*  edata    = (float*) (ws + off); off += (size_t)N_EDGES * REC_F * 4;
    int*    counts   = (int*)   (ws + off); off += (size_t)N_NODES * 4 + 960;
    int*    cursor   = (int*)   (ws + off); off += (size_t)N_NODES * 4 + 960;
    (void)ws_size;

    hipMemsetAsync(counts, 0, (size_t)N_NODES * 4, stream);

    // A: fused prep (out copy + mu pack + weight repack + histogram)
    prep_kernel<<<A_Q + A_MU + A_PK + A_W + A_H, 256, 0, stream>>>(
        (const float4*)q, (const float4*)mu, mu, Wf2, W1, W2, Wf1, bf1, ei,
        (float4*)d_out, (ushort4*)src_pack, Wf2b, W1b, W2b, Wf1b, counts);

    // C: exclusive scan -> cursor
    scan_kernel<<<1, SCAN_NT, 0, stream>>>(counts, cursor);

    // D: node MLP + sort-scatter of physical edge records
    node_scatter_kernel<<<D_NODE + D_SCAT, 512, 0, stream>>>(
        q, W1b, b1, W2b, b2, ei, cursor, rbf, uv, cut, edata, src_pack);

    // E: edge kernel over sorted records (XCD-chunked swizzle)
    edge_kernel<<<N_EDGES / 32, 512, 0, stream>>>(
        src_pack, edata, Wf1b, Wf2b, bf2, out_q, out_mu);
}